// Round 8
// baseline (829.145 us; speedup 1.0000x reference)
//
#include <hip/hip_runtime.h>

#define NEGV -1e9f

// workspace layout (float offsets)
#define OFF_X1   0u               // 1048576  emb@W_ih^T + b (k2-only; k3 reuses head as A_T)
#define OFF_XX   1048576u         // 1048576  emb@Wx^T + b_cell
#define OFF_A    2097152u         // 262144   Aemb = Ws_b + emb@Ws3^T (row-major)
#define OFF_SH   2359296u         // 262144   shared LSTM outputs
#define OFF_SWM  2621440u         // 1048576  shared@Wm^T
#define OFF_HX2  3670016u         // 16384 floats = 8192 u64 (k2 h exchange)
#define OFF_HX4  3686400u         // 16384 floats (k4 h exchange)
#define OFF_AT   OFF_X1           // 262144   A transposed [b][k=256][s=64] (written by k3)

__device__ __forceinline__ float sigf(float x) { return 1.f / (1.f + __expf(-x)); }
__device__ __forceinline__ float tanhfast(float x) {
  float e = __expf(2.f * x);
  return 1.f - __fdividef(2.f, e + 1.f);
}

__device__ __forceinline__ unsigned long long gloadU64(const unsigned long long* p) {
  return __hip_atomic_load(p, __ATOMIC_RELAXED, __HIP_MEMORY_SCOPE_AGENT);
}
__device__ __forceinline__ void gstoreU64(unsigned long long* p, unsigned long long v) {
  __hip_atomic_store(p, v, __ATOMIC_RELAXED, __HIP_MEMORY_SCOPE_AGENT);
}
__device__ __forceinline__ unsigned long long packTV(unsigned tag, float v) {
  return ((unsigned long long)tag << 32) | (unsigned long long)__float_as_uint(v);
}
// pack two f32 as bf16 (round-to-nearest): lo16 <- a, hi16 <- b
__device__ __forceinline__ unsigned packbf2(float a, float b) {
  unsigned ua = (__float_as_uint(a) + 0x8000u) >> 16;
  unsigned ub = (__float_as_uint(b) + 0x8000u) & 0xFFFF0000u;
  return ua | ub;
}
__device__ __forceinline__ float bflo(unsigned u) { return __uint_as_float(u << 16); }
__device__ __forceinline__ float bfhi(unsigned u) { return __uint_as_float(u & 0xFFFF0000u); }

// 16-row x 128-col output tile GEMM helper, K=256. eL: [16][260], wL: [128][68]
__device__ __forceinline__ void tile_mm(const float* __restrict__ W, int ldw, int wcol0,
                                        int j0, const float* eL, float* wL, float acc[8]) {
  const int i = threadIdx.x >> 4, jj = threadIdx.x & 15;
  for (int kc = 0; kc < 4; ++kc) {
    __syncthreads();
    const int k0 = kc * 64;
    #pragma unroll
    for (int m = 0; m < 32; ++m) {
      int v = threadIdx.x + (m << 8);
      int row = v >> 6, col = v & 63;
      wL[row * 68 + col] = W[(j0 + row) * ldw + wcol0 + k0 + col];
    }
    __syncthreads();
    const float* ebase = eL + i * 260 + k0;
    #pragma unroll 4
    for (int k4 = 0; k4 < 16; ++k4) {
      float4 e4 = *(const float4*)(ebase + k4 * 4);
      #pragma unroll
      for (int u = 0; u < 8; ++u) {
        float4 w4 = *(const float4*)(wL + (jj + (u << 4)) * 68 + k4 * 4);
        acc[u] += e4.x * w4.x + e4.y * w4.y + e4.z * w4.z + e4.w * w4.w;
      }
    }
  }
}

// K1: emb gather + X1 = emb@W_ih^T + (b_ih+b_hh); Xx = emb@Wx^T + b_cell;
//     Aemb = emb@Ws3^T + Ws_b. Zero-inits both h exchange buffers.
__global__ __launch_bounds__(256) void k1_precompute(
    const int* __restrict__ x, const float* __restrict__ embed,
    const float* __restrict__ W_ih, const float* __restrict__ b_ih,
    const float* __restrict__ b_hh, const float* __restrict__ Ws_w,
    const float* __restrict__ Ws_b, const float* __restrict__ Wx,
    const float* __restrict__ b_cell, float* __restrict__ ws) {
  __shared__ float eL[16 * 260];
  __shared__ float wL[128 * 68];
  const int rt = blockIdx.x / 18, jb = blockIdx.x % 18;
  if (blockIdx.x == 0) {
    for (int i = threadIdx.x; i < 32768; i += 256) ws[OFF_HX2 + i] = 0.f;
  }
  for (int i = 0; i < 16; ++i) {
    int xi = x[rt * 16 + i];
    eL[i * 260 + threadIdx.x] = embed[xi * 256 + threadIdx.x];
  }
  const float* W; const float* bias1; const float* bias2 = nullptr;
  int ldw, wcol0, j0, ostride; float* out;
  if (jb < 8)       { W = W_ih; ldw = 256; wcol0 = 0;   j0 = jb * 128;        out = ws + OFF_X1; ostride = 1024; bias1 = b_ih; bias2 = b_hh; }
  else if (jb < 16) { W = Wx;   ldw = 256; wcol0 = 0;   j0 = (jb - 8) * 128;  out = ws + OFF_XX; ostride = 1024; bias1 = b_cell; }
  else              { W = Ws_w; ldw = 768; wcol0 = 512; j0 = (jb - 16) * 128; out = ws + OFF_A;  ostride = 256;  bias1 = Ws_b; }
  float acc[8];
  #pragma unroll
  for (int u = 0; u < 8; ++u) acc[u] = 0.f;
  tile_mm(W, ldw, wcol0, j0, eL, wL, acc);
  const int i = threadIdx.x >> 4, jj = threadIdx.x & 15;
  const int r = rt * 16 + i;
  #pragma unroll
  for (int u = 0; u < 8; ++u) {
    int j = j0 + jj + (u << 4);
    float bv = bias1[j] + (bias2 ? bias2[j] : 0.f);
    out[r * ostride + j] = acc[u] + bv;
  }
}

// K2: shared LSTM. grid 128 = 16 batches x 8 WGs, 512 threads.
// R5 structure + wave-local gates (no gA, no 2nd barrier) + parity-dbuf hPar.
// Per step: 1 poll RT (t<256, 1 spin each) + 1 barrier.
__global__ __launch_bounds__(512) void k2_shared_lstm(
    const float* __restrict__ W_hh, float* __restrict__ ws) {
  const int b = blockIdx.x & 15, j = blockIdx.x >> 4;
  const int t = threadIdx.x;
  const int w = t >> 6, l = t & 63;
  const int gate = l >> 4, u = (l >> 2) & 3, q = l & 3;
  const int nn = (w << 2) + u;                 // hidden unit 0..31 (local)
  const int r = (gate << 5) + nn;              // local row 0..127
  const int grow = (gate << 8) + (j << 5) + nn;
  __shared__ float x1L[8192];
  __shared__ __align__(16) float hPar[2][256];
  unsigned long long* hx = (unsigned long long*)(ws + OFF_HX2);
  float* sh = ws + OFF_SH;
  const float* X1 = ws + OFF_X1;

  float4 wv[16];
  {
    const float* wp = W_hh + grow * 256 + (q << 6);
    #pragma unroll
    for (int m = 0; m < 16; ++m) wv[m] = *(const float4*)(wp + 4 * m);
  }
  for (int v = t; v < 8192; v += 512) {
    int st = v >> 7, rr = v & 127;
    int col = ((rr >> 5) << 8) + (j << 5) + (rr & 31);
    x1L[v] = X1[(b * 64 + st) * 1024 + col];
  }
  float c_reg = 0.f;
  const bool owner = (gate == 0) && (q == 0);
  __syncthreads();

  for (int st = 0; st < 64; ++st) {
    if (t < 256) {
      const unsigned long long* p = hx + (unsigned)(st & 1) * 4096u + b * 256 + t;
      unsigned long long v = gloadU64(p);
      while ((unsigned)(v >> 32) < (unsigned)st) v = gloadU64(p);
      hPar[st & 1][t] = __uint_as_float((unsigned)v);
    }
    __syncthreads();
    const float* hp = hPar[st & 1] + (q << 6);
    float p = 0.f;
    #pragma unroll
    for (int m = 0; m < 16; ++m) {
      float4 h4 = *(const float4*)(hp + 4 * m);
      p += wv[m].x * h4.x + wv[m].y * h4.y + wv[m].z * h4.z + wv[m].w * h4.w;
    }
    if (q == 0) p += x1L[(st << 7) + r];
    p += __shfl_xor(p, 1); p += __shfl_xor(p, 2);   // quad now holds full row dot
    float gf = __shfl(p, l + 16);                   // forget gate row (wave-local)
    float gg = __shfl(p, l + 32);
    float go = __shfl(p, l + 48);
    if (owner) {
      c_reg = sigf(gf) * c_reg + sigf(p) * tanhfast(gg);
      float hn = sigf(go) * tanhfast(c_reg);
      sh[(b * 64 + st) * 256 + (j << 5) + nn] = hn;
      gstoreU64(hx + (unsigned)((st + 1) & 1) * 4096u + b * 256 + (j << 5) + nn,
                packTV(st + 1, hn));
    }
    // no trailing barrier: next step writes hPar[(st+1)&1] (other parity), and
    // the per-iteration barrier bounds wave skew to <1 step.
  }
}

// K3: A_T[b][k][s] = Aemb + shared@Ws1^T (transposed into dead X1 head);
//     SWM = shared@Wm^T (row-major).
__global__ __launch_bounds__(256) void k3_precompute2(
    const float* __restrict__ Ws_w, const float* __restrict__ Wm,
    float* __restrict__ ws) {
  __shared__ float eL[16 * 260];
  __shared__ float wL[128 * 68];
  const int rt = blockIdx.x / 10, jb = blockIdx.x % 10;
  const float* sh = ws + OFF_SH;
  for (int i = 0; i < 16; ++i)
    eL[i * 260 + threadIdx.x] = sh[(rt * 16 + i) * 256 + threadIdx.x];
  const float* W; int ldw, wcol0, j0; bool addmode;
  if (jb < 8) { W = Wm;   ldw = 256; wcol0 = 0; j0 = jb * 128;       addmode = false; }
  else        { W = Ws_w; ldw = 768; wcol0 = 0; j0 = (jb - 8) * 128; addmode = true; }
  float acc[8];
  #pragma unroll
  for (int u = 0; u < 8; ++u) acc[u] = 0.f;
  tile_mm(W, ldw, wcol0, j0, eL, wL, acc);
  const int i = threadIdx.x >> 4, jj = threadIdx.x & 15;
  const int r = rt * 16 + i;
  if (addmode) {
    const float* Aemb = ws + OFF_A;
    float* AT = ws + OFF_AT;
    const int bb = r >> 6, s = r & 63;
    #pragma unroll
    for (int u = 0; u < 8; ++u) {
      int j = j0 + jj + (u << 4);
      AT[bb * 16384 + j * 64 + s] = Aemb[r * 256 + j] + acc[u];
    }
  } else {
    float* out = ws + OFF_SWM;
    #pragma unroll
    for (int u = 0; u < 8; ++u) {
      int j = j0 + jj + (u << 4);
      out[r * 1024 + j] = acc[u];
    }
  }
}

// K4: task LSTM + attention. grid 128 = 16 batches x 8 WGs, 512 threads.
// LOCAL hw via bf16-replicated Ws2 (64 VGPR) + bf16 Wh quarter-rows (32 VGPR)
// -> 96 persistent regs, no spill, NO psi exchange. 1 RT + 3 barriers/step.
__global__ __launch_bounds__(512) void k4_task_lstm(
    const int* __restrict__ mask, const float* __restrict__ Ws_w,
    const float* __restrict__ Us_w, const float* __restrict__ Wh,
    const float* __restrict__ fc_w, const float* __restrict__ fc_b,
    float* __restrict__ ws, float* __restrict__ out) {
  const int b = blockIdx.x & 15, j = blockIdx.x >> 4;
  const int t = threadIdx.x;
  const int w = t >> 6, l = t & 63;
  const int gate = l >> 4, u = (l >> 2) & 3, q = l & 3;
  const int nn = (w << 2) + u;
  const int r = (gate << 5) + nn;
  const int grow = (gate << 8) + (j << 5) + nn;
  const int row2 = t >> 1, half2 = t & 1;      // hw rows: wave w owns [32w,32w+32)

  __shared__ __align__(16) float aT[256 * 65];     // 66560 B  A^T [k][s] pad65
  __shared__ __align__(16) float swmB[10240];      // 40960 B  [s/16][r][16]
  __shared__ __align__(16) float usL[256];
  __shared__ __align__(16) float hL[256];
  __shared__ float part[512];
  __shared__ __align__(16) float attL[64];
  __shared__ float redL[4];
  __shared__ int   mL[64];

  unsigned long long* hx = (unsigned long long*)(ws + OFF_HX4);
  const float* AT  = ws + OFF_AT;
  const float* SWM = ws + OFF_SWM;
  const float* Xx  = ws + OFF_XX;

  // ---- bf16 weights into registers (96 VGPR persistent) ----
  unsigned w2b[64];   // Ws2 half-row: row2, cols half2*128..+128 (packed pairs)
  {
    const float* p2 = Ws_w + row2 * 768 + 256 + (half2 << 7);
    #pragma unroll
    for (int m = 0; m < 64; ++m) w2b[m] = packbf2(p2[2 * m], p2[2 * m + 1]);
  }
  unsigned whb[32];   // Wh quarter-row: grow, cols q*64..+64 (packed pairs)
  {
    const float* pw = Wh + grow * 256 + (q << 6);
    #pragma unroll
    for (int m = 0; m < 32; ++m) whb[m] = packbf2(pw[2 * m], pw[2 * m + 1]);
  }
  // ---- LDS staging ----
  for (int v = t; v < 16384; v += 512)
    aT[(v >> 6) * 65 + (v & 63)] = AT[b * 16384 + v];
  for (int v = t; v < 8192; v += 512) {
    int s = v >> 7, rr = v & 127;
    int col = ((rr >> 5) << 8) + (j << 5) + (rr & 31);
    swmB[(s >> 4) * 2560 + rr * 20 + (s & 15)] = SWM[(b * 64 + s) * 1024 + col];
  }
  if (t < 256) usL[t] = Us_w[t];
  if (t < 64) mL[t] = mask[b * 64 + t];
  float c_reg = 0.f;
  const bool owner = (gate == 0) && (q == 0);
  __syncthreads();

  for (int st = 0; st < 64; ++st) {
    float xx_r = (q == 0) ? Xx[(b * 64 + st) * 1024 + grow] : 0.f;
    // ---- poll h (t<256, one element, one spin) ----
    if (t < 256) {
      const unsigned long long* p = hx + (unsigned)(st & 1) * 4096u + b * 256 + t;
      unsigned long long v = gloadU64(p);
      while ((unsigned)(v >> 32) < (unsigned)st) v = gloadU64(p);
      hL[t] = __uint_as_float((unsigned)v);
    }
    __syncthreads();                                   // S1
    // ---- hw (replicated, wave-local rows, bf16 weights) ----
    float ph = 0.f;
    {
      const float* hp = hL + (half2 << 7);
      #pragma unroll
      for (int m = 0; m < 64; ++m)
        ph += bflo(w2b[m]) * hp[2 * m] + bfhi(w2b[m]) * hp[2 * m + 1];
      ph += __shfl_xor(ph, 1);   // pair-reduce: lanes 2i,2i+1 hold hw row 32w+i
    }
    // ---- psi partials over own wave's k-chunk (hw via uniform shfl) ----
    float ps = 0.f;
    {
      const int k0 = w << 5;
      #pragma unroll
      for (int i2 = 0; i2 < 32; ++i2) {
        float hwv = __shfl(ph, i2 << 1);
        ps += usL[k0 + i2] * tanhfast(aT[(k0 + i2) * 65 + l] + hwv);
      }
      part[t] = ps;
    }
    // ---- pwh = h@Wh^T quarter-dot (bf16 weights, LDS h) ----
    float pwh = 0.f;
    {
      const float* hp = hL + (q << 6);
      #pragma unroll
      for (int m = 0; m < 32; ++m)
        pwh += bflo(whb[m]) * hp[2 * m] + bfhi(whb[m]) * hp[2 * m + 1];
    }
    __syncthreads();                                   // S2
    // ---- Si + mask + softmax (wave 0) ----
    if (t < 64) {
      float vr = 0.f;
      #pragma unroll
      for (int w2 = 0; w2 < 8; ++w2) vr += part[(w2 << 6) + t];
      vr = mL[t] ? vr : NEGV;
      float mx = vr;
      #pragma unroll
      for (int d = 1; d < 64; d <<= 1) mx = fmaxf(mx, __shfl_xor(mx, d));
      float e2 = __expf(vr - mx);
      float ssum = e2;
      #pragma unroll
      for (int d = 1; d < 64; d <<= 1) ssum += __shfl_xor(ssum, d);
      attL[t] = e2 / ssum;
    }
    __syncthreads();                                   // S3
    // ---- g = xx + pwh + att@SWM; wave-local gates; publish h ----
    {
      float p = pwh;
      const float* sb = swmB + q * 2560 + r * 20;
      const float* ab = attL + (q << 4);
      #pragma unroll
      for (int i2 = 0; i2 < 4; ++i2) {
        float4 s4 = *(const float4*)(sb + 4 * i2);
        float4 a4 = *(const float4*)(ab + 4 * i2);
        p += s4.x * a4.x + s4.y * a4.y + s4.z * a4.z + s4.w * a4.w;
      }
      if (q == 0) p += xx_r;
      p += __shfl_xor(p, 1); p += __shfl_xor(p, 2);
      float gf = __shfl(p, l + 16);
      float gg = __shfl(p, l + 32);
      float go = __shfl(p, l + 48);
      if (owner) {
        c_reg = sigf(gf) * c_reg + sigf(p) * tanhfast(gg);
        float hn = sigf(go) * tanhfast(c_reg);
        gstoreU64(hx + (unsigned)((st + 1) & 1) * 4096u + b * 256 + (j << 5) + nn,
                  packTV(st + 1, hn));
      }
    }
  }

  // ---- final classifier (WG j==0 per batch) ----
  if (j == 0) {
    float v = 0.f;
    if (t < 256) {
      const unsigned long long* p = hx + 0 * 4096u + b * 256 + t;  // slot 64&1==0
      unsigned long long vv = gloadU64(p);
      while ((unsigned)(vv >> 32) < 64u) vv = gloadU64(p);
      v = __uint_as_float((unsigned)vv) * fc_w[t];
    }
    #pragma unroll
    for (int d = 1; d < 64; d <<= 1) v += __shfl_xor(v, d);
    if (t < 256 && (t & 63) == 0) redL[t >> 6] = v;
    __syncthreads();
    if (t == 0) out[b] = sigf(redL[0] + redL[1] + redL[2] + redL[3] + fc_b[0]);
  }
}

extern "C" void kernel_launch(void* const* d_in, const int* in_sizes, int n_in,
                              void* d_out, int out_size, void* d_ws, size_t ws_size,
                              hipStream_t stream) {
  const int*   x      = (const int*)d_in[0];
  const int*   mask   = (const int*)d_in[1];
  const float* embed  = (const float*)d_in[3];
  const float* W_ih   = (const float*)d_in[4];
  const float* W_hh   = (const float*)d_in[5];
  const float* b_ih   = (const float*)d_in[6];
  const float* b_hh   = (const float*)d_in[7];
  const float* Ws_w   = (const float*)d_in[8];
  const float* Ws_b   = (const float*)d_in[9];
  const float* Us_w   = (const float*)d_in[10];
  const float* Wx     = (const float*)d_in[12];
  const float* Wh     = (const float*)d_in[13];
  const float* Wm     = (const float*)d_in[14];
  const float* b_cell = (const float*)d_in[15];
  const float* fc_w   = (const float*)d_in[16];
  const float* fc_b   = (const float*)d_in[17];
  float* ws  = (float*)d_ws;
  float* out = (float*)d_out;

  k1_precompute<<<dim3(1152), dim3(256), 0, stream>>>(
      x, embed, W_ih, b_ih, b_hh, Ws_w, Ws_b, Wx, b_cell, ws);
  k2_shared_lstm<<<dim3(128), dim3(512), 0, stream>>>(W_hh, ws);
  k3_precompute2<<<dim3(640), dim3(256), 0, stream>>>(Ws_w, Wm, ws);
  k4_task_lstm<<<dim3(128), dim3(512), 0, stream>>>(
      mask, Ws_w, Us_w, Wh, fc_w, fc_b, ws, out);
}

// Round 9
// 773.533 us; speedup vs baseline: 1.0719x; 1.0719x over previous
//
#include <hip/hip_runtime.h>

#define NEGV -1e9f

// workspace layout (float offsets)
#define OFF_X1   0u               // 1048576  emb@W_ih^T + b (k2-only; k3 reuses head as A_T)
#define OFF_XX   1048576u         // 1048576  emb@Wx^T + b_cell
#define OFF_A    2097152u         // 262144   Aemb = Ws_b + emb@Ws3^T (row-major)
#define OFF_SH   2359296u         // 262144   shared LSTM outputs
#define OFF_SWM  2621440u         // 1048576  shared@Wm^T
#define OFF_HX2  3670016u         // 16384 floats = 8192 u64 (k2 h exchange)
#define OFF_HX4  3686400u         // 16384 floats (k4 h exchange)
#define OFF_AT   OFF_X1           // 262144   A transposed [b][k=256][s=64] (written by k3)

__device__ __forceinline__ float sigf(float x) { return 1.f / (1.f + __expf(-x)); }
__device__ __forceinline__ float tanhfast(float x) {
  float e = __expf(2.f * x);
  return 1.f - __fdividef(2.f, e + 1.f);
}

__device__ __forceinline__ unsigned long long gloadU64(const unsigned long long* p) {
  return __hip_atomic_load(p, __ATOMIC_RELAXED, __HIP_MEMORY_SCOPE_AGENT);
}
__device__ __forceinline__ void gstoreU64(unsigned long long* p, unsigned long long v) {
  __hip_atomic_store(p, v, __ATOMIC_RELAXED, __HIP_MEMORY_SCOPE_AGENT);
}
__device__ __forceinline__ unsigned long long packTV(unsigned tag, float v) {
  return ((unsigned long long)tag << 32) | (unsigned long long)__float_as_uint(v);
}
// pack two f32 as bf16 (round-to-nearest): lo16 <- a, hi16 <- b
__device__ __forceinline__ unsigned packbf2(float a, float b) {
  unsigned ua = (__float_as_uint(a) + 0x8000u) >> 16;
  unsigned ub = (__float_as_uint(b) + 0x8000u) & 0xFFFF0000u;
  return ua | ub;
}
__device__ __forceinline__ float bflo(unsigned u) { return __uint_as_float(u << 16); }
__device__ __forceinline__ float bfhi(unsigned u) { return __uint_as_float(u & 0xFFFF0000u); }

// 16-row x 128-col output tile GEMM helper, K=256. eL: [16][260], wL: [128][68]
__device__ __forceinline__ void tile_mm(const float* __restrict__ W, int ldw, int wcol0,
                                        int j0, const float* eL, float* wL, float acc[8]) {
  const int i = threadIdx.x >> 4, jj = threadIdx.x & 15;
  for (int kc = 0; kc < 4; ++kc) {
    __syncthreads();
    const int k0 = kc * 64;
    #pragma unroll
    for (int m = 0; m < 32; ++m) {
      int v = threadIdx.x + (m << 8);
      int row = v >> 6, col = v & 63;
      wL[row * 68 + col] = W[(j0 + row) * ldw + wcol0 + k0 + col];
    }
    __syncthreads();
    const float* ebase = eL + i * 260 + k0;
    #pragma unroll 4
    for (int k4 = 0; k4 < 16; ++k4) {
      float4 e4 = *(const float4*)(ebase + k4 * 4);
      #pragma unroll
      for (int u = 0; u < 8; ++u) {
        float4 w4 = *(const float4*)(wL + (jj + (u << 4)) * 68 + k4 * 4);
        acc[u] += e4.x * w4.x + e4.y * w4.y + e4.z * w4.z + e4.w * w4.w;
      }
    }
  }
}

// K1: emb gather + X1 = emb@W_ih^T + (b_ih+b_hh); Xx = emb@Wx^T + b_cell;
//     Aemb = emb@Ws3^T + Ws_b. Zero-inits both h exchange buffers.
__global__ __launch_bounds__(256) void k1_precompute(
    const int* __restrict__ x, const float* __restrict__ embed,
    const float* __restrict__ W_ih, const float* __restrict__ b_ih,
    const float* __restrict__ b_hh, const float* __restrict__ Ws_w,
    const float* __restrict__ Ws_b, const float* __restrict__ Wx,
    const float* __restrict__ b_cell, float* __restrict__ ws) {
  __shared__ float eL[16 * 260];
  __shared__ float wL[128 * 68];
  const int rt = blockIdx.x / 18, jb = blockIdx.x % 18;
  if (blockIdx.x == 0) {
    for (int i = threadIdx.x; i < 32768; i += 256) ws[OFF_HX2 + i] = 0.f;
  }
  for (int i = 0; i < 16; ++i) {
    int xi = x[rt * 16 + i];
    eL[i * 260 + threadIdx.x] = embed[xi * 256 + threadIdx.x];
  }
  const float* W; const float* bias1; const float* bias2 = nullptr;
  int ldw, wcol0, j0, ostride; float* out;
  if (jb < 8)       { W = W_ih; ldw = 256; wcol0 = 0;   j0 = jb * 128;        out = ws + OFF_X1; ostride = 1024; bias1 = b_ih; bias2 = b_hh; }
  else if (jb < 16) { W = Wx;   ldw = 256; wcol0 = 0;   j0 = (jb - 8) * 128;  out = ws + OFF_XX; ostride = 1024; bias1 = b_cell; }
  else              { W = Ws_w; ldw = 768; wcol0 = 512; j0 = (jb - 16) * 128; out = ws + OFF_A;  ostride = 256;  bias1 = Ws_b; }
  float acc[8];
  #pragma unroll
  for (int u = 0; u < 8; ++u) acc[u] = 0.f;
  tile_mm(W, ldw, wcol0, j0, eL, wL, acc);
  const int i = threadIdx.x >> 4, jj = threadIdx.x & 15;
  const int r = rt * 16 + i;
  #pragma unroll
  for (int u = 0; u < 8; ++u) {
    int j = j0 + jj + (u << 4);
    float bv = bias1[j] + (bias2 ? bias2[j] : 0.f);
    out[r * ostride + j] = acc[u] + bv;
  }
}

// K2: shared LSTM. grid 128 = 16 batches x 8 WGs, 512 threads.
// Wave-local gates + parity-dbuf hPar: 1 poll RT + 1 barrier per step.
__global__ __launch_bounds__(512) void k2_shared_lstm(
    const float* __restrict__ W_hh, float* __restrict__ ws) {
  const int b = blockIdx.x & 15, j = blockIdx.x >> 4;
  const int t = threadIdx.x;
  const int w = t >> 6, l = t & 63;
  const int gate = l >> 4, u = (l >> 2) & 3, q = l & 3;
  const int nn = (w << 2) + u;                 // hidden unit 0..31 (local)
  const int r = (gate << 5) + nn;              // local row 0..127
  const int grow = (gate << 8) + (j << 5) + nn;
  __shared__ float x1L[8192];
  __shared__ __align__(16) float hPar[2][256];
  unsigned long long* hx = (unsigned long long*)(ws + OFF_HX2);
  float* sh = ws + OFF_SH;
  const float* X1 = ws + OFF_X1;

  float4 wv[16];
  {
    const float* wp = W_hh + grow * 256 + (q << 6);
    #pragma unroll
    for (int m = 0; m < 16; ++m) wv[m] = *(const float4*)(wp + 4 * m);
  }
  for (int v = t; v < 8192; v += 512) {
    int st = v >> 7, rr = v & 127;
    int col = ((rr >> 5) << 8) + (j << 5) + (rr & 31);
    x1L[v] = X1[(b * 64 + st) * 1024 + col];
  }
  float c_reg = 0.f;
  const bool owner = (gate == 0) && (q == 0);
  __syncthreads();

  for (int st = 0; st < 64; ++st) {
    if (t < 256) {
      const unsigned long long* p = hx + (unsigned)(st & 1) * 4096u + b * 256 + t;
      unsigned long long v = gloadU64(p);
      while ((unsigned)(v >> 32) < (unsigned)st) v = gloadU64(p);
      hPar[st & 1][t] = __uint_as_float((unsigned)v);
    }
    __syncthreads();
    const float* hp = hPar[st & 1] + (q << 6);
    float p = 0.f;
    #pragma unroll
    for (int m = 0; m < 16; ++m) {
      float4 h4 = *(const float4*)(hp + 4 * m);
      p += wv[m].x * h4.x + wv[m].y * h4.y + wv[m].z * h4.z + wv[m].w * h4.w;
    }
    if (q == 0) p += x1L[(st << 7) + r];
    p += __shfl_xor(p, 1); p += __shfl_xor(p, 2);   // quad holds full row dot
    float gf = __shfl(p, l + 16);
    float gg = __shfl(p, l + 32);
    float go = __shfl(p, l + 48);
    if (owner) {
      c_reg = sigf(gf) * c_reg + sigf(p) * tanhfast(gg);
      float hn = sigf(go) * tanhfast(c_reg);
      sh[(b * 64 + st) * 256 + (j << 5) + nn] = hn;
      gstoreU64(hx + (unsigned)((st + 1) & 1) * 4096u + b * 256 + (j << 5) + nn,
                packTV(st + 1, hn));
    }
  }
}

// K3: A_T[b][k][s] = Aemb + shared@Ws1^T (transposed into dead X1 head);
//     SWM = shared@Wm^T (row-major).
__global__ __launch_bounds__(256) void k3_precompute2(
    const float* __restrict__ Ws_w, const float* __restrict__ Wm,
    float* __restrict__ ws) {
  __shared__ float eL[16 * 260];
  __shared__ float wL[128 * 68];
  const int rt = blockIdx.x / 10, jb = blockIdx.x % 10;
  const float* sh = ws + OFF_SH;
  for (int i = 0; i < 16; ++i)
    eL[i * 260 + threadIdx.x] = sh[(rt * 16 + i) * 256 + threadIdx.x];
  const float* W; int ldw, wcol0, j0; bool addmode;
  if (jb < 8) { W = Wm;   ldw = 256; wcol0 = 0; j0 = jb * 128;       addmode = false; }
  else        { W = Ws_w; ldw = 768; wcol0 = 0; j0 = (jb - 8) * 128; addmode = true; }
  float acc[8];
  #pragma unroll
  for (int u = 0; u < 8; ++u) acc[u] = 0.f;
  tile_mm(W, ldw, wcol0, j0, eL, wL, acc);
  const int i = threadIdx.x >> 4, jj = threadIdx.x & 15;
  const int r = rt * 16 + i;
  if (addmode) {
    const float* Aemb = ws + OFF_A;
    float* AT = ws + OFF_AT;
    const int bb = r >> 6, s = r & 63;
    #pragma unroll
    for (int u = 0; u < 8; ++u) {
      int j = j0 + jj + (u << 4);
      AT[bb * 16384 + j * 64 + s] = Aemb[r * 256 + j] + acc[u];
    }
  } else {
    float* out = ws + OFF_SWM;
    #pragma unroll
    for (int u = 0; u < 8; ++u) {
      int j = j0 + jj + (u << 4);
      out[r * 1024 + j] = acc[u];
    }
  }
}

// K4: task LSTM + attention. grid 128 = 16 batches x 8 WGs, 512 threads.
// Local hw via bf16-replicated Ws2 (64 VGPR); Wh STREAMED from L2 each step
// (no persistent Wh regs -> ~70 persistent, under the 128 cap, no spill).
// Per-wave replicated softmax. 1 RT + 2 barriers per step, NO psi exchange.
__global__ __launch_bounds__(512) void k4_task_lstm(
    const int* __restrict__ mask, const float* __restrict__ Ws_w,
    const float* __restrict__ Us_w, const float* __restrict__ Wh,
    const float* __restrict__ fc_w, const float* __restrict__ fc_b,
    float* __restrict__ ws, float* __restrict__ out) {
  const int b = blockIdx.x & 15, j = blockIdx.x >> 4;
  const int t = threadIdx.x;
  const int w = t >> 6, l = t & 63;
  const int gate = l >> 4, u = (l >> 2) & 3, q = l & 3;
  const int nn = (w << 2) + u;
  const int r = (gate << 5) + nn;
  const int grow = (gate << 8) + (j << 5) + nn;
  const int half2 = t & 1;                     // hw: 2 threads/row; wave w owns rows [32w,32w+32)

  __shared__ __align__(16) float aT[256 * 65];     // 66560 B  A^T [k][s] pad65
  __shared__ __align__(16) float swmB[10240];      // 40960 B  [s/16][r][16]
  __shared__ __align__(16) float usL[256];
  __shared__ __align__(16) float hL[256];
  __shared__ float part[512];
  __shared__ __align__(16) float attW[512];        // per-wave softmax copies
  __shared__ float redL[4];
  __shared__ int   mL[64];

  unsigned long long* hx = (unsigned long long*)(ws + OFF_HX4);
  const float* AT  = ws + OFF_AT;
  const float* SWM = ws + OFF_SWM;
  const float* Xx  = ws + OFF_XX;

  // ---- bf16 Ws2 replicated into registers (64 VGPR persistent) ----
  unsigned w2b[64];   // Ws2 half-row: row (t>>1), cols half2*128..+128 (packed pairs)
  {
    const float* p2 = Ws_w + (t >> 1) * 768 + 256 + (half2 << 7);
    #pragma unroll
    for (int m = 0; m < 64; ++m) w2b[m] = packbf2(p2[2 * m], p2[2 * m + 1]);
  }
  // ---- LDS staging ----
  for (int v = t; v < 16384; v += 512)
    aT[(v >> 6) * 65 + (v & 63)] = AT[b * 16384 + v];
  for (int v = t; v < 8192; v += 512) {
    int s = v >> 7, rr = v & 127;
    int col = ((rr >> 5) << 8) + (j << 5) + (rr & 31);
    swmB[(s >> 4) * 2560 + rr * 20 + (s & 15)] = SWM[(b * 64 + s) * 1024 + col];
  }
  if (t < 256) usL[t] = Us_w[t];
  if (t < 64) mL[t] = mask[b * 64 + t];
  float c_reg = 0.f;
  const bool owner = (gate == 0) && (q == 0);
  __syncthreads();

  for (int st = 0; st < 64; ++st) {
    float xx_r = (q == 0) ? Xx[(b * 64 + st) * 1024 + grow] : 0.f;
    // ---- poll h (t<256, one element, one spin) ----
    if (t < 256) {
      const unsigned long long* p = hx + (unsigned)(st & 1) * 4096u + b * 256 + t;
      unsigned long long v = gloadU64(p);
      while ((unsigned)(v >> 32) < (unsigned)st) v = gloadU64(p);
      hL[t] = __uint_as_float((unsigned)v);
    }
    __syncthreads();                                   // S1
    // ---- hw (replicated, wave-local rows, bf16 weights in regs) ----
    float ph = 0.f;
    {
      const float* hp = hL + (half2 << 7);
      #pragma unroll
      for (int m = 0; m < 64; ++m)
        ph += bflo(w2b[m]) * hp[2 * m] + bfhi(w2b[m]) * hp[2 * m + 1];
      ph += __shfl_xor(ph, 1);   // lanes 2i,2i+1 hold hw row 32w+i
    }
    // ---- psi partials over own wave's k-chunk (hw via uniform shfl) ----
    {
      float ps = 0.f;
      const int k0 = w << 5;
      #pragma unroll
      for (int i2 = 0; i2 < 32; ++i2) {
        float hwv = __shfl(ph, i2 << 1);
        ps += usL[k0 + i2] * tanhfast(aT[(k0 + i2) * 65 + l] + hwv);
      }
      part[t] = ps;
    }
    // ---- pwh = h@Wh^T quarter-dot (Wh streamed from L2, capped unroll) ----
    float pwh = 0.f;
    {
      const float* pw = Wh + grow * 256 + (q << 6);
      const float* hp = hL + (q << 6);
      #pragma unroll 4
      for (int m = 0; m < 16; ++m) {
        float4 w4 = *(const float4*)(pw + 4 * m);
        pwh += w4.x * hp[4 * m] + w4.y * hp[4 * m + 1]
             + w4.z * hp[4 * m + 2] + w4.w * hp[4 * m + 3];
      }
    }
    __syncthreads();                                   // S2
    // ---- Si + mask + softmax (replicated per wave; own attW range) ----
    {
      float vr = 0.f;
      #pragma unroll
      for (int w2 = 0; w2 < 8; ++w2) vr += part[(w2 << 6) + l];
      vr = mL[l] ? vr : NEGV;
      float mx = vr;
      #pragma unroll
      for (int d = 1; d < 64; d <<= 1) mx = fmaxf(mx, __shfl_xor(mx, d));
      float e2 = __expf(vr - mx);
      float ssum = e2;
      #pragma unroll
      for (int d = 1; d < 64; d <<= 1) ssum += __shfl_xor(ssum, d);
      attW[t] = e2 / ssum;       // wave-private copy, same-wave read below
    }
    // ---- g = xx + pwh + att@SWM; wave-local gates; publish h ----
    {
      float p = pwh;
      const float* sb = swmB + q * 2560 + r * 20;
      const float* ab = attW + (w << 6) + (q << 4);
      #pragma unroll
      for (int i2 = 0; i2 < 4; ++i2) {
        float4 s4 = *(const float4*)(sb + 4 * i2);
        float4 a4 = *(const float4*)(ab + 4 * i2);
        p += s4.x * a4.x + s4.y * a4.y + s4.z * a4.z + s4.w * a4.w;
      }
      if (q == 0) p += xx_r;
      p += __shfl_xor(p, 1); p += __shfl_xor(p, 2);
      float gf = __shfl(p, l + 16);
      float gg = __shfl(p, l + 32);
      float go = __shfl(p, l + 48);
      if (owner) {
        c_reg = sigf(gf) * c_reg + sigf(p) * tanhfast(gg);
        float hn = sigf(go) * tanhfast(c_reg);
        gstoreU64(hx + (unsigned)((st + 1) & 1) * 4096u + b * 256 + (j << 5) + nn,
                  packTV(st + 1, hn));
      }
    }
  }

  // ---- final classifier (WG j==0 per batch) ----
  if (j == 0) {
    float v = 0.f;
    if (t < 256) {
      const unsigned long long* p = hx + 0 * 4096u + b * 256 + t;  // slot 64&1==0
      unsigned long long vv = gloadU64(p);
      while ((unsigned)(vv >> 32) < 64u) vv = gloadU64(p);
      v = __uint_as_float((unsigned)vv) * fc_w[t];
    }
    #pragma unroll
    for (int d = 1; d < 64; d <<= 1) v += __shfl_xor(v, d);
    if (t < 256 && (t & 63) == 0) redL[t >> 6] = v;
    __syncthreads();
    if (t == 0) out[b] = sigf(redL[0] + redL[1] + redL[2] + redL[3] + fc_b[0]);
  }
}

extern "C" void kernel_launch(void* const* d_in, const int* in_sizes, int n_in,
                              void* d_out, int out_size, void* d_ws, size_t ws_size,
                              hipStream_t stream) {
  const int*   x      = (const int*)d_in[0];
  const int*   mask   = (const int*)d_in[1];
  const float* embed  = (const float*)d_in[3];
  const float* W_ih   = (const float*)d_in[4];
  const float* W_hh   = (const float*)d_in[5];
  const float* b_ih   = (const float*)d_in[6];
  const float* b_hh   = (const float*)d_in[7];
  const float* Ws_w   = (const float*)d_in[8];
  const float* Ws_b   = (const float*)d_in[9];
  const float* Us_w   = (const float*)d_in[10];
  const float* Wx     = (const float*)d_in[12];
  const float* Wh     = (const float*)d_in[13];
  const float* Wm     = (const float*)d_in[14];
  const float* b_cell = (const float*)d_in[15];
  const float* fc_w   = (const float*)d_in[16];
  const float* fc_b   = (const float*)d_in[17];
  float* ws  = (float*)d_ws;
  float* out = (float*)d_out;

  k1_precompute<<<dim3(1152), dim3(256), 0, stream>>>(
      x, embed, W_ih, b_ih, b_hh, Ws_w, Ws_b, Wx, b_cell, ws);
  k2_shared_lstm<<<dim3(128), dim3(512), 0, stream>>>(W_hh, ws);
  k3_precompute2<<<dim3(640), dim3(256), 0, stream>>>(Ws_w, Wm, ws);
  k4_task_lstm<<<dim3(128), dim3(512), 0, stream>>>(
      mask, Ws_w, Us_w, Wh, fc_w, fc_b, ws, out);
}

// Round 10
// 521.320 us; speedup vs baseline: 1.5905x; 1.4838x over previous
//
#include <hip/hip_runtime.h>

#define NEGV -1e9f

// workspace layout (float offsets)
#define OFF_X1   0u               // 1048576  emb@W_ih^T + b (k2-only; k3 reuses head as A_T)
#define OFF_XX   1048576u         // 1048576  emb@Wx^T + b_cell
#define OFF_A    2097152u         // 262144   Aemb = Ws_b + emb@Ws3^T (row-major)
#define OFF_SH   2359296u         // 262144   shared LSTM outputs
#define OFF_SWM  2621440u         // 1048576  shared@Wm^T
#define OFF_HX2  3670016u         // 16384 floats = 8192 u64 (k2 h exchange)
#define OFF_HX4  3686400u         // 16384 floats (k4 h exchange)
#define OFF_PSI  3702784u         // 32768 floats = 2 slots x 16 x 512 u64 (k4 psi exchange)
#define OFF_AT   OFF_X1           // 262144   A transposed [b][k=256][s=64] (written by k3)

__device__ __forceinline__ float sigf(float x) { return 1.f / (1.f + __expf(-x)); }
__device__ __forceinline__ float tanhfast(float x) {
  float e = __expf(2.f * x);
  return 1.f - __fdividef(2.f, e + 1.f);
}

__device__ __forceinline__ unsigned long long gloadU64(const unsigned long long* p) {
  return __hip_atomic_load(p, __ATOMIC_RELAXED, __HIP_MEMORY_SCOPE_AGENT);
}
__device__ __forceinline__ void gstoreU64(unsigned long long* p, unsigned long long v) {
  __hip_atomic_store(p, v, __ATOMIC_RELAXED, __HIP_MEMORY_SCOPE_AGENT);
}
__device__ __forceinline__ unsigned long long packTV(unsigned tag, float v) {
  return ((unsigned long long)tag << 32) | (unsigned long long)__float_as_uint(v);
}

// 16-row x 128-col output tile GEMM helper, K=256. eL: [16][260], wL: [128][68]
__device__ __forceinline__ void tile_mm(const float* __restrict__ W, int ldw, int wcol0,
                                        int j0, const float* eL, float* wL, float acc[8]) {
  const int i = threadIdx.x >> 4, jj = threadIdx.x & 15;
  for (int kc = 0; kc < 4; ++kc) {
    __syncthreads();
    const int k0 = kc * 64;
    #pragma unroll
    for (int m = 0; m < 32; ++m) {
      int v = threadIdx.x + (m << 8);
      int row = v >> 6, col = v & 63;
      wL[row * 68 + col] = W[(j0 + row) * ldw + wcol0 + k0 + col];
    }
    __syncthreads();
    const float* ebase = eL + i * 260 + k0;
    #pragma unroll 4
    for (int k4 = 0; k4 < 16; ++k4) {
      float4 e4 = *(const float4*)(ebase + k4 * 4);
      #pragma unroll
      for (int u = 0; u < 8; ++u) {
        float4 w4 = *(const float4*)(wL + (jj + (u << 4)) * 68 + k4 * 4);
        acc[u] += e4.x * w4.x + e4.y * w4.y + e4.z * w4.z + e4.w * w4.w;
      }
    }
  }
}

// K1: emb gather + X1 = emb@W_ih^T + (b_ih+b_hh); Xx = emb@Wx^T + b_cell;
//     Aemb = emb@Ws3^T + Ws_b. Zero-inits ALL exchange buffers (HX2/HX4/PSI).
__global__ __launch_bounds__(256) void k1_precompute(
    const int* __restrict__ x, const float* __restrict__ embed,
    const float* __restrict__ W_ih, const float* __restrict__ b_ih,
    const float* __restrict__ b_hh, const float* __restrict__ Ws_w,
    const float* __restrict__ Ws_b, const float* __restrict__ Wx,
    const float* __restrict__ b_cell, float* __restrict__ ws) {
  __shared__ float eL[16 * 260];
  __shared__ float wL[128 * 68];
  const int rt = blockIdx.x / 18, jb = blockIdx.x % 18;
  if (blockIdx.x == 0) {
    for (int i = threadIdx.x; i < 65536; i += 256) ws[OFF_HX2 + i] = 0.f;
  }
  for (int i = 0; i < 16; ++i) {
    int xi = x[rt * 16 + i];
    eL[i * 260 + threadIdx.x] = embed[xi * 256 + threadIdx.x];
  }
  const float* W; const float* bias1; const float* bias2 = nullptr;
  int ldw, wcol0, j0, ostride; float* out;
  if (jb < 8)       { W = W_ih; ldw = 256; wcol0 = 0;   j0 = jb * 128;        out = ws + OFF_X1; ostride = 1024; bias1 = b_ih; bias2 = b_hh; }
  else if (jb < 16) { W = Wx;   ldw = 256; wcol0 = 0;   j0 = (jb - 8) * 128;  out = ws + OFF_XX; ostride = 1024; bias1 = b_cell; }
  else              { W = Ws_w; ldw = 768; wcol0 = 512; j0 = (jb - 16) * 128; out = ws + OFF_A;  ostride = 256;  bias1 = Ws_b; }
  float acc[8];
  #pragma unroll
  for (int u = 0; u < 8; ++u) acc[u] = 0.f;
  tile_mm(W, ldw, wcol0, j0, eL, wL, acc);
  const int i = threadIdx.x >> 4, jj = threadIdx.x & 15;
  const int r = rt * 16 + i;
  #pragma unroll
  for (int u = 0; u < 8; ++u) {
    int j = j0 + jj + (u << 4);
    float bv = bias1[j] + (bias2 ? bias2[j] : 0.f);
    out[r * ostride + j] = acc[u] + bv;
  }
}

// K2: shared LSTM. grid 128 = 16 batches x 8 WGs, 512 threads.
// Wave-local gates + parity-dbuf hPar: 1 poll RT + 1 barrier per step.
__global__ __launch_bounds__(512) void k2_shared_lstm(
    const float* __restrict__ W_hh, float* __restrict__ ws) {
  const int b = blockIdx.x & 15, j = blockIdx.x >> 4;
  const int t = threadIdx.x;
  const int w = t >> 6, l = t & 63;
  const int gate = l >> 4, u = (l >> 2) & 3, q = l & 3;
  const int nn = (w << 2) + u;                 // hidden unit 0..31 (local)
  const int r = (gate << 5) + nn;              // local row 0..127
  const int grow = (gate << 8) + (j << 5) + nn;
  __shared__ float x1L[8192];
  __shared__ __align__(16) float hPar[2][256];
  unsigned long long* hx = (unsigned long long*)(ws + OFF_HX2);
  float* sh = ws + OFF_SH;
  const float* X1 = ws + OFF_X1;

  float4 wv[16];
  {
    const float* wp = W_hh + grow * 256 + (q << 6);
    #pragma unroll
    for (int m = 0; m < 16; ++m) wv[m] = *(const float4*)(wp + 4 * m);
  }
  for (int v = t; v < 8192; v += 512) {
    int st = v >> 7, rr = v & 127;
    int col = ((rr >> 5) << 8) + (j << 5) + (rr & 31);
    x1L[v] = X1[(b * 64 + st) * 1024 + col];
  }
  float c_reg = 0.f;
  const bool owner = (gate == 0) && (q == 0);
  __syncthreads();

  for (int st = 0; st < 64; ++st) {
    if (t < 256) {
      const unsigned long long* p = hx + (unsigned)(st & 1) * 4096u + b * 256 + t;
      unsigned long long v = gloadU64(p);
      while ((unsigned)(v >> 32) < (unsigned)st) v = gloadU64(p);
      hPar[st & 1][t] = __uint_as_float((unsigned)v);
    }
    __syncthreads();
    const float* hp = hPar[st & 1] + (q << 6);
    float p = 0.f;
    #pragma unroll
    for (int m = 0; m < 16; ++m) {
      float4 h4 = *(const float4*)(hp + 4 * m);
      p += wv[m].x * h4.x + wv[m].y * h4.y + wv[m].z * h4.z + wv[m].w * h4.w;
    }
    if (q == 0) p += x1L[(st << 7) + r];
    p += __shfl_xor(p, 1); p += __shfl_xor(p, 2);   // quad holds full row dot
    float gf = __shfl(p, l + 16);
    float gg = __shfl(p, l + 32);
    float go = __shfl(p, l + 48);
    if (owner) {
      c_reg = sigf(gf) * c_reg + sigf(p) * tanhfast(gg);
      float hn = sigf(go) * tanhfast(c_reg);
      sh[(b * 64 + st) * 256 + (j << 5) + nn] = hn;
      gstoreU64(hx + (unsigned)((st + 1) & 1) * 4096u + b * 256 + (j << 5) + nn,
                packTV(st + 1, hn));
    }
  }
}

// K3: A_T[b][k][s] = Aemb + shared@Ws1^T (transposed into dead X1 head);
//     SWM = shared@Wm^T (row-major).
__global__ __launch_bounds__(256) void k3_precompute2(
    const float* __restrict__ Ws_w, const float* __restrict__ Wm,
    float* __restrict__ ws) {
  __shared__ float eL[16 * 260];
  __shared__ float wL[128 * 68];
  const int rt = blockIdx.x / 10, jb = blockIdx.x % 10;
  const float* sh = ws + OFF_SH;
  for (int i = 0; i < 16; ++i)
    eL[i * 260 + threadIdx.x] = sh[(rt * 16 + i) * 256 + threadIdx.x];
  const float* W; int ldw, wcol0, j0; bool addmode;
  if (jb < 8) { W = Wm;   ldw = 256; wcol0 = 0; j0 = jb * 128;       addmode = false; }
  else        { W = Ws_w; ldw = 768; wcol0 = 0; j0 = (jb - 8) * 128; addmode = true; }
  float acc[8];
  #pragma unroll
  for (int u = 0; u < 8; ++u) acc[u] = 0.f;
  tile_mm(W, ldw, wcol0, j0, eL, wL, acc);
  const int i = threadIdx.x >> 4, jj = threadIdx.x & 15;
  const int r = rt * 16 + i;
  if (addmode) {
    const float* Aemb = ws + OFF_A;
    float* AT = ws + OFF_AT;
    const int bb = r >> 6, s = r & 63;
    #pragma unroll
    for (int u = 0; u < 8; ++u) {
      int j = j0 + jj + (u << 4);
      AT[bb * 16384 + j * 64 + s] = Aemb[r * 256 + j] + acc[u];
    }
  } else {
    float* out = ws + OFF_SWM;
    #pragma unroll
    for (int u = 0; u < 8; ++u) {
      int j = j0 + jj + (u << 4);
      out[r * 1024 + j] = acc[u];
    }
  }
}

// K4: task LSTM + attention. grid 128 = 16 batches x 8 WGs, 512 threads.
// R5 dataflow (distributed hw + psi exchange, f32 weights in regs ~80 VGPR)
// with: wave-local hw (shfl, no LDS/barrier), spread psi/h publishes,
// per-wave replicated softmax, early first psi probe. 2 RT + 3 barriers/step.
__global__ __launch_bounds__(512) void k4_task_lstm(
    const int* __restrict__ mask, const float* __restrict__ Ws_w,
    const float* __restrict__ Us_w, const float* __restrict__ Wh,
    const float* __restrict__ fc_w, const float* __restrict__ fc_b,
    float* __restrict__ ws, float* __restrict__ out) {
  const int b = blockIdx.x & 15, j = blockIdx.x >> 4;
  const int t = threadIdx.x;
  const int w = t >> 6, l = t & 63;
  const int gate = l >> 4, u = (l >> 2) & 3, q = l & 3;
  const int nn = (w << 2) + u;                 // hidden unit 0..31 (local)
  const int r = (gate << 5) + nn;              // g row 0..127 (local)
  const int grow = (gate << 8) + (j << 5) + nn;
  const int hwrow = t >> 4, hwc = t & 15;      // hw: wave w owns local k in [4w,4w+4)

  __shared__ __align__(16) float aTo[32 * 65];     // 8320 B  own A^T chunk [kk][s]
  __shared__ __align__(16) float swmB[10240];      // 40960 B [s/16][r][16]
  __shared__ __align__(16) float hL[256];
  __shared__ float usOwn[32];
  __shared__ float part[512];
  __shared__ float psiA[512];
  __shared__ __align__(16) float attW[512];        // per-wave softmax copies
  __shared__ float redL[4];
  __shared__ int   mL[64];

  unsigned long long* hx   = (unsigned long long*)(ws + OFF_HX4);
  unsigned long long* psiX = (unsigned long long*)(ws + OFF_PSI);
  const float* AT  = ws + OFF_AT;
  const float* SWM = ws + OFF_SWM;
  const float* Xx  = ws + OFF_XX;

  // ---- weights into registers (~80 VGPR persistent) ----
  float4 w2v[4];    // Ws2 row (32j+hwrow), cols hwc*16..+16
  {
    const float* p2 = Ws_w + (j * 32 + hwrow) * 768 + 256 + (hwc << 4);
    #pragma unroll
    for (int m = 0; m < 4; ++m) w2v[m] = *(const float4*)(p2 + 4 * m);
  }
  float4 whv[16];   // Wh quarter-row (grow, cols q*64..+64)
  {
    const float* pw = Wh + grow * 256 + (q << 6);
    #pragma unroll
    for (int m = 0; m < 16; ++m) whv[m] = *(const float4*)(pw + 4 * m);
  }
  // ---- LDS staging ----
  for (int v = t; v < 2048; v += 512)   // own A^T k-chunk, coalesced
    aTo[(v >> 6) * 65 + (v & 63)] = AT[b * 16384 + j * 2048 + v];
  for (int v = t; v < 8192; v += 512) {
    int s = v >> 7, rr = v & 127;
    int col = ((rr >> 5) << 8) + (j << 5) + (rr & 31);
    swmB[(s >> 4) * 2560 + rr * 20 + (s & 15)] = SWM[(b * 64 + s) * 1024 + col];
  }
  if (t < 32) usOwn[t] = Us_w[j * 32 + t];
  if (t < 64) mL[t] = mask[b * 64 + t];
  float c_reg = 0.f;
  const bool owner = (gate == 0) && (q == 0);
  __syncthreads();

  for (int st = 0; st < 64; ++st) {
    // early Xx prefetch (one per g-row, q==0 lanes)
    float xx_r = (q == 0) ? Xx[(b * 64 + st) * 1024 + grow] : 0.f;
    // ---- poll h (t<256, one element, one spin) ----
    if (t < 256) {
      const unsigned long long* p = hx + (unsigned)(st & 1) * 4096u + b * 256 + t;
      unsigned long long v = gloadU64(p);
      while ((unsigned)(v >> 32) < (unsigned)st) v = gloadU64(p);
      hL[t] = __uint_as_float((unsigned)v);
    }
    __syncthreads();                                   // S1
    // ---- hw own rows, wave-local: 16 threads/row, value shared via shfl ----
    float ph;
    {
      const float* hp = hL + (hwc << 4);
      float p = 0.f;
      #pragma unroll
      for (int m = 0; m < 4; ++m) {
        float4 h4 = *(const float4*)(hp + 4 * m);
        p += w2v[m].x * h4.x + w2v[m].y * h4.y + w2v[m].z * h4.z + w2v[m].w * h4.w;
      }
      p += __shfl_xor(p, 1); p += __shfl_xor(p, 2);
      p += __shfl_xor(p, 4); p += __shfl_xor(p, 8);
      ph = p;   // all 16 lanes of row-group hold hw row (4w + (l>>4))
    }
    // ---- psi partials over own wave's 4 k's (hw via uniform shfl) ----
    {
      float ps = 0.f;
      #pragma unroll
      for (int i2 = 0; i2 < 4; ++i2) {
        float hwv = __shfl(ph, (w << 6 & 0) + (i2 << 4));  // lane i2*16 of this wave
        int kk = (w << 2) + i2;
        ps += usOwn[kk] * tanhfast(aTo[kk * 65 + l] + hwv);
      }
      part[t] = ps;
    }
    __syncthreads();                                   // S2: part[] complete
    // ---- spread psi reduce + publish: 8 lanes per wave, s = 8w + l ----
    if (l < 8) {
      int s = (w << 3) + l;
      float red = part[s] + part[64 + s] + part[128 + s] + part[192 + s]
                + part[256 + s] + part[320 + s] + part[384 + s] + part[448 + s];
      gstoreU64(psiX + ((unsigned)(st & 1) * 16u + b) * 512u + (j << 6) + s,
                packTV(st + 1, red));
    }
    // ---- first psi probe in flight, then pwh to hide its latency ----
    const unsigned long long* pp =
        psiX + ((unsigned)(st & 1) * 16u + b) * 512u + t;
    unsigned long long pv = gloadU64(pp);
    float pwh = 0.f;
    {
      const float* hp = hL + (q << 6);
      #pragma unroll
      for (int m = 0; m < 16; ++m) {
        float4 h4 = *(const float4*)(hp + 4 * m);
        pwh += whv[m].x * h4.x + whv[m].y * h4.y + whv[m].z * h4.z + whv[m].w * h4.w;
      }
    }
    while ((unsigned)(pv >> 32) < (unsigned)(st + 1)) pv = gloadU64(pp);
    psiA[t] = __uint_as_float((unsigned)pv);
    __syncthreads();                                   // S3: psiA complete
    // ---- Si assembly + mask + softmax (replicated per wave) ----
    {
      float vr = psiA[l] + psiA[64 + l] + psiA[128 + l] + psiA[192 + l]
               + psiA[256 + l] + psiA[320 + l] + psiA[384 + l] + psiA[448 + l];
      vr = mL[l] ? vr : NEGV;
      float mx = vr;
      #pragma unroll
      for (int d = 1; d < 64; d <<= 1) mx = fmaxf(mx, __shfl_xor(mx, d));
      float e2 = __expf(vr - mx);
      float ssum = e2;
      #pragma unroll
      for (int d = 1; d < 64; d <<= 1) ssum += __shfl_xor(ssum, d);
      attW[t] = e2 / ssum;       // wave-private copy
    }
    // ---- g = xx + pwh + att@SWM; wave-local gates; publish h (no barrier) ----
    {
      float p = pwh;
      const float* sb = swmB + q * 2560 + r * 20;
      const float* ab = attW + (w << 6) + (q << 4);
      #pragma unroll
      for (int i2 = 0; i2 < 4; ++i2) {
        float4 s4 = *(const float4*)(sb + 4 * i2);
        float4 a4 = *(const float4*)(ab + 4 * i2);
        p += s4.x * a4.x + s4.y * a4.y + s4.z * a4.z + s4.w * a4.w;
      }
      if (q == 0) p += xx_r;
      p += __shfl_xor(p, 1); p += __shfl_xor(p, 2);
      float gf = __shfl(p, l + 16);
      float gg = __shfl(p, l + 32);
      float go = __shfl(p, l + 48);
      if (owner) {
        c_reg = sigf(gf) * c_reg + sigf(p) * tanhfast(gg);
        float hn = sigf(go) * tanhfast(c_reg);
        gstoreU64(hx + (unsigned)((st + 1) & 1) * 4096u + b * 256 + (j << 5) + nn,
                  packTV(st + 1, hn));
      }
    }
  }

  // ---- final classifier (WG j==0 per batch) ----
  if (j == 0) {
    float v = 0.f;
    if (t < 256) {
      const unsigned long long* p = hx + 0 * 4096u + b * 256 + t;  // slot 64&1==0
      unsigned long long vv = gloadU64(p);
      while ((unsigned)(vv >> 32) < 64u) vv = gloadU64(p);
      v = __uint_as_float((unsigned)vv) * fc_w[t];
    }
    #pragma unroll
    for (int d = 1; d < 64; d <<= 1) v += __shfl_xor(v, d);
    if (t < 256 && (t & 63) == 0) redL[t >> 6] = v;
    __syncthreads();
    if (t == 0) out[b] = sigf(redL[0] + redL[1] + redL[2] + redL[3] + fc_b[0]);
  }
}

extern "C" void kernel_launch(void* const* d_in, const int* in_sizes, int n_in,
                              void* d_out, int out_size, void* d_ws, size_t ws_size,
                              hipStream_t stream) {
  const int*   x      = (const int*)d_in[0];
  const int*   mask   = (const int*)d_in[1];
  const float* embed  = (const float*)d_in[3];
  const float* W_ih   = (const float*)d_in[4];
  const float* W_hh   = (const float*)d_in[5];
  const float* b_ih   = (const float*)d_in[6];
  const float* b_hh   = (const float*)d_in[7];
  const float* Ws_w   = (const float*)d_in[8];
  const float* Ws_b   = (const float*)d_in[9];
  const float* Us_w   = (const float*)d_in[10];
  const float* Wx     = (const float*)d_in[12];
  const float* Wh     = (const float*)d_in[13];
  const float* Wm     = (const float*)d_in[14];
  const float* b_cell = (const float*)d_in[15];
  const float* fc_w   = (const float*)d_in[16];
  const float* fc_b   = (const float*)d_in[17];
  float* ws  = (float*)d_ws;
  float* out = (float*)d_out;

  k1_precompute<<<dim3(1152), dim3(256), 0, stream>>>(
      x, embed, W_ih, b_ih, b_hh, Ws_w, Ws_b, Wx, b_cell, ws);
  k2_shared_lstm<<<dim3(128), dim3(512), 0, stream>>>(W_hh, ws);
  k3_precompute2<<<dim3(640), dim3(256), 0, stream>>>(Ws_w, Wm, ws);
  k4_task_lstm<<<dim3(128), dim3(512), 0, stream>>>(
      mask, Ws_w, Us_w, Wh, fc_w, fc_b, ws, out);
}